// Round 1
// baseline (1400.092 us; speedup 1.0000x reference)
//
#include <hip/hip_runtime.h>

#define B_ 4
#define N_ 2048
#define R_ (B_ * N_)      // 8192 rows
#define HID_ 256
#define EMB_ 64
#define IN_DIM_ 70
#define H_ 4
#define HEAD_ 64
#define FFN_ 512
#define LAYERS_ 4

// ---------------------------------------------------------------------------
// Repack val_W [L][H][HID][HEAD] -> Wv [L][HID][H*HEAD] so V-proj is a
// standard row-major GEMM with output col c = h*64+d.
// ---------------------------------------------------------------------------
__global__ __launch_bounds__(256) void repack_valW(const float* __restrict__ valW,
                                                   float* __restrict__ Wv) {
    int idx = blockIdx.x * 256 + threadIdx.x;   // 4*256*256 = 262144 total
    int c = idx & 255;
    int f = (idx >> 8) & 255;
    int l = idx >> 16;
    int h = c >> 6, d = c & 63;
    Wv[idx] = valW[(((l * H_ + h) * HID_ + f) * HEAD_) + d];
}

// ---------------------------------------------------------------------------
// Input MLP: feats = relu(concat(xc, emb, lat) @ in_W + in_b)   [8192][256]
// ---------------------------------------------------------------------------
__global__ __launch_bounds__(256) void input_mlp(const float* __restrict__ xc,
                                                 const float* __restrict__ emb,
                                                 const float* __restrict__ lat,
                                                 const float* __restrict__ W,
                                                 const float* __restrict__ b,
                                                 float* __restrict__ feats) {
    __shared__ float xr[8][IN_DIM_ + 2];
    int t = threadIdx.x;
    int row0 = blockIdx.x * 8;
    for (int idx = t; idx < 8 * IN_DIM_; idx += 256) {
        int r = idx / IN_DIM_, f = idx % IN_DIM_;
        int rr = row0 + r;
        float v;
        if (f < 3)       v = xc[rr * 3 + f];
        else if (f < 67) v = emb[rr * EMB_ + (f - 3)];
        else             v = lat[rr * 3 + (f - 67)];
        xr[r][f] = v;
    }
    __syncthreads();
    float acc[8] = {0.f, 0.f, 0.f, 0.f, 0.f, 0.f, 0.f, 0.f};
    for (int f = 0; f < IN_DIM_; ++f) {
        float w = W[f * HID_ + t];
#pragma unroll
        for (int r = 0; r < 8; ++r) acc[r] += xr[r][f] * w;
    }
    float bb = b[t];
#pragma unroll
    for (int r = 0; r < 8; ++r) {
        float v = acc[r] + bb;
        feats[(row0 + r) * HID_ + t] = v > 0.f ? v : 0.f;
    }
}

// ---------------------------------------------------------------------------
// Generic fp32 GEMM: out[R][COLS] = X[R][KD] @ W[KD][COLS] (+epilogues)
// Block: 16 rows x 256 cols, 256 threads, thread = 4x4 accs.
// MODE 0: +bias                (V-proj)
// MODE 1: +bias, relu          (FFN1, out-MLP1)
// MODE 2: +bias, +resid, LN    (attn-proj+LN1, FFN2+LN2)  [COLS must be 256]
// ---------------------------------------------------------------------------
template <int KD, int COLS, int MODE>
__global__ __launch_bounds__(256) void gemm16(const float* __restrict__ X,
                                              const float* __restrict__ W,
                                              const float* __restrict__ bias,
                                              const float* __restrict__ resid,
                                              const float* __restrict__ g,
                                              const float* __restrict__ bln,
                                              float* __restrict__ out) {
    __shared__ float Xs[16][33];
    __shared__ float Ws[32][256];
    int t = threadIdx.x;
    int row0 = blockIdx.x * 16;
    int cbase = blockIdx.y * 256;
    int c0 = (t & 63) * 4;
    int r0 = (t >> 6) * 4;
    float acc[4][4] = {};

    for (int kt = 0; kt < KD; kt += 32) {
        {
            int idx = t;
#pragma unroll
            for (int rep = 0; rep < 2; ++rep, idx += 256) {
                int r = idx >> 5, k = idx & 31;
                Xs[r][k] = X[(row0 + r) * KD + kt + k];
            }
        }
#pragma unroll
        for (int rep = 0; rep < 8; ++rep) {
            int k = (t >> 6) + rep * 4;
            *(float4*)&Ws[k][(t & 63) * 4] =
                *(const float4*)&W[(kt + k) * COLS + cbase + (t & 63) * 4];
        }
        __syncthreads();
#pragma unroll
        for (int k = 0; k < 32; ++k) {
            float4 wv = *(float4*)&Ws[k][c0];
#pragma unroll
            for (int i = 0; i < 4; ++i) {
                float xv = Xs[r0 + i][k];
                acc[i][0] += xv * wv.x; acc[i][1] += xv * wv.y;
                acc[i][2] += xv * wv.z; acc[i][3] += xv * wv.w;
            }
        }
        __syncthreads();
    }

    if (MODE == 2) {
        float vals[4][4];
        float s1[4] = {0.f, 0.f, 0.f, 0.f}, s2[4] = {0.f, 0.f, 0.f, 0.f};
#pragma unroll
        for (int i = 0; i < 4; ++i) {
            int row = row0 + r0 + i;
#pragma unroll
            for (int j = 0; j < 4; ++j) {
                float v = acc[i][j] + bias[c0 + j] + resid[row * 256 + c0 + j];
                vals[i][j] = v;
                s1[i] += v;
                s2[i] += v * v;
            }
        }
#pragma unroll
        for (int off = 1; off < 64; off <<= 1) {
#pragma unroll
            for (int i = 0; i < 4; ++i) {
                s1[i] += __shfl_xor(s1[i], off, 64);
                s2[i] += __shfl_xor(s2[i], off, 64);
            }
        }
#pragma unroll
        for (int i = 0; i < 4; ++i) {
            float mu = s1[i] * (1.f / 256.f);
            float var = s2[i] * (1.f / 256.f) - mu * mu;
            float rstd = rsqrtf(var + 1e-5f);
            int row = row0 + r0 + i;
#pragma unroll
            for (int j = 0; j < 4; ++j) {
                out[row * 256 + c0 + j] =
                    (vals[i][j] - mu) * rstd * g[c0 + j] + bln[c0 + j];
            }
        }
    } else {
#pragma unroll
        for (int i = 0; i < 4; ++i) {
            int row = row0 + r0 + i;
#pragma unroll
            for (int j = 0; j < 4; ++j) {
                float v = acc[i][j] + bias[cbase + c0 + j];
                if (MODE == 1) v = fmaxf(v, 0.f);
                out[row * COLS + cbase + c0 + j] = v;
            }
        }
    }
}

// ---------------------------------------------------------------------------
// RBF attention: O[b,i,(h,d)] = (sum_j exp(-d2(i,j)/ls2[h]) * V[b,j,h,d])
//                               / (sum_j exp(-d2(i,j)/ls2[h]) + 1e-8)
// E recomputed on the fly from coords; denominator folded into the same pass.
// Block = (b, 32-row i-tile), 256 threads; j-tiles of 32.
// Output threads: col0=(t&63)*4 (4 cols), i0=(t>>6)*8 (8 rows) -> 32 accs.
// E-builder threads: h=t>>6, i=(t>>1)&31, j-half=t&1 -> 16 exps/tile.
// ---------------------------------------------------------------------------
__global__ __launch_bounds__(256) void attn_pv(const float* __restrict__ xc,
                                               const float* __restrict__ V,
                                               float* __restrict__ O) {
    __shared__ float ci[32][4];
    __shared__ float cj[32][4];
    __shared__ float Es[32][4][40];   // [jj][h][i], pad 40 -> bank-clean reads
    __shared__ float Vs[32][256];
    __shared__ float dnm[4][32];

    int t = threadIdx.x;
    int b = blockIdx.y;
    int i_base = blockIdx.x * 32;

    int c0 = (t & 63) * 4;          // output col (h*64+d)
    int h_out = c0 >> 6;
    int i0 = (t >> 6) * 8;          // output row group

    int h_e = t >> 6;               // E-builder head
    int i_e = (t >> 1) & 31;        // E-builder row
    int jh = (t & 1) * 16;          // E-builder j-half

    const float inv_ls2[4] = {4.0f, 1.0f, 0.25f, 0.0625f};
    float my_inv = inv_ls2[h_e];

    if (t < 32) {
        int rr = b * N_ + i_base + t;
        ci[t][0] = xc[rr * 3 + 0];
        ci[t][1] = xc[rr * 3 + 1];
        ci[t][2] = xc[rr * 3 + 2];
    }
    float acc[8][4] = {};
    float denom = 0.f;
    __syncthreads();
    float cix = ci[i_e][0], ciy = ci[i_e][1], ciz = ci[i_e][2];

    for (int jt = 0; jt < N_; jt += 32) {
        if (t < 32) {
            int rr = b * N_ + jt + t;
            cj[t][0] = xc[rr * 3 + 0];
            cj[t][1] = xc[rr * 3 + 1];
            cj[t][2] = xc[rr * 3 + 2];
        }
#pragma unroll
        for (int rep = 0; rep < 8; ++rep) {
            int jj = (t >> 6) + rep * 4;
            *(float4*)&Vs[jj][(t & 63) * 4] =
                *(const float4*)&V[(b * N_ + jt + jj) * 256 + (t & 63) * 4];
        }
        __syncthreads();

        float rs = 0.f;
#pragma unroll
        for (int s = 0; s < 16; ++s) {
            int jj = jh + s;
            float dx = cix - cj[jj][0];
            float dy = ciy - cj[jj][1];
            float dz = ciz - cj[jj][2];
            float d2 = dx * dx + dy * dy + dz * dz;
            float e = __expf(-d2 * my_inv);
            Es[jj][h_e][i_e] = e;
            rs += e;
        }
        rs += __shfl_xor(rs, 1, 64);   // partner j-half -> full 32-j rowsum
        denom += rs;
        __syncthreads();

#pragma unroll 4
        for (int jj = 0; jj < 32; ++jj) {
            float4 vv = *(float4*)&Vs[jj][c0];
            float4 e0 = *(float4*)&Es[jj][h_out][i0];
            float4 e1 = *(float4*)&Es[jj][h_out][i0 + 4];
            float ev[8] = {e0.x, e0.y, e0.z, e0.w, e1.x, e1.y, e1.z, e1.w};
#pragma unroll
            for (int r = 0; r < 8; ++r) {
                acc[r][0] += ev[r] * vv.x;
                acc[r][1] += ev[r] * vv.y;
                acc[r][2] += ev[r] * vv.z;
                acc[r][3] += ev[r] * vv.w;
            }
        }
        __syncthreads();
    }

    if ((t & 1) == 0) dnm[h_e][i_e] = denom;
    __syncthreads();

#pragma unroll
    for (int r = 0; r < 8; ++r) {
        float invd = 1.f / (dnm[h_out][i0 + r] + 1e-8f);
        int row = b * N_ + i_base + i0 + r;
        float4 o;
        o.x = acc[r][0] * invd;
        o.y = acc[r][1] * invd;
        o.z = acc[r][2] * invd;
        o.w = acc[r][3] * invd;
        *(float4*)&O[row * 256 + c0] = o;
    }
}

// ---------------------------------------------------------------------------
// Final projection: out[row][0..2] = relu_h1[row] @ out_W2 + out_b2
// One wave per row; butterfly reduce.
// ---------------------------------------------------------------------------
__global__ __launch_bounds__(256) void out_proj(const float* __restrict__ X,
                                                const float* __restrict__ W2,
                                                const float* __restrict__ b2,
                                                float* __restrict__ out) {
    int t = threadIdx.x;
    int lane = t & 63, w = t >> 6;
    int row = blockIdx.x * 4 + w;
    float4 x = *(const float4*)&X[row * 256 + lane * 4];
    float xv[4] = {x.x, x.y, x.z, x.w};
    float a0 = 0.f, a1 = 0.f, a2 = 0.f;
#pragma unroll
    for (int kk = 0; kk < 4; ++kk) {
        const float* wr = &W2[(lane * 4 + kk) * 3];
        a0 += xv[kk] * wr[0];
        a1 += xv[kk] * wr[1];
        a2 += xv[kk] * wr[2];
    }
#pragma unroll
    for (int off = 1; off < 64; off <<= 1) {
        a0 += __shfl_xor(a0, off, 64);
        a1 += __shfl_xor(a1, off, 64);
        a2 += __shfl_xor(a2, off, 64);
    }
    if (lane == 0) {
        out[row * 3 + 0] = a0 + b2[0];
        out[row * 3 + 1] = a1 + b2[1];
        out[row * 3 + 2] = a2 + b2[2];
    }
}

// ---------------------------------------------------------------------------
extern "C" void kernel_launch(void* const* d_in, const int* in_sizes, int n_in,
                              void* d_out, int out_size, void* d_ws, size_t ws_size,
                              hipStream_t stream) {
    const float* lat    = (const float*)d_in[0];
    const float* xc     = (const float*)d_in[1];
    const float* emb    = (const float*)d_in[2];
    const float* in_W   = (const float*)d_in[3];
    const float* in_b   = (const float*)d_in[4];
    const float* val_W  = (const float*)d_in[5];
    const float* val_b  = (const float*)d_in[6];
    const float* attn_W = (const float*)d_in[7];
    const float* attn_b = (const float*)d_in[8];
    const float* ln1_g  = (const float*)d_in[9];
    const float* ln1_b  = (const float*)d_in[10];
    const float* ln2_g  = (const float*)d_in[11];
    const float* ln2_b  = (const float*)d_in[12];
    const float* ffn_W1 = (const float*)d_in[13];
    const float* ffn_b1 = (const float*)d_in[14];
    const float* ffn_W2 = (const float*)d_in[15];
    const float* ffn_b2 = (const float*)d_in[16];
    const float* out_W1 = (const float*)d_in[17];
    const float* out_b1 = (const float*)d_in[18];
    const float* out_W2 = (const float*)d_in[19];
    const float* out_b2 = (const float*)d_in[20];

    float* ws    = (float*)d_ws;
    float* feats = ws;                       // 8192*256
    float* att   = ws + 2097152;             // 8192*256
    float* Vbuf  = ws + 2 * 2097152;         // 8192*256 (also out-MLP hidden)
    float* hid   = ws + 3 * 2097152;         // 8192*512
    float* Wv    = ws + 3 * 2097152 + 4194304;  // 4*256*256

    repack_valW<<<1024, 256, 0, stream>>>(val_W, Wv);
    input_mlp<<<R_ / 8, 256, 0, stream>>>(xc, emb, lat, in_W, in_b, feats);

    for (int l = 0; l < LAYERS_; ++l) {
        gemm16<256, 256, 0><<<dim3(R_ / 16, 1), 256, 0, stream>>>(
            feats, Wv + l * 65536, val_b + l * 256,
            nullptr, nullptr, nullptr, Vbuf);
        attn_pv<<<dim3(N_ / 32, B_), 256, 0, stream>>>(xc, Vbuf, att);
        gemm16<256, 256, 2><<<dim3(R_ / 16, 1), 256, 0, stream>>>(
            att, attn_W + l * 65536, attn_b + l * 256,
            feats, ln1_g + l * 256, ln1_b + l * 256, feats);
        gemm16<256, 512, 1><<<dim3(R_ / 16, 2), 256, 0, stream>>>(
            feats, ffn_W1 + l * 131072, ffn_b1 + l * 512,
            nullptr, nullptr, nullptr, hid);
        gemm16<512, 256, 2><<<dim3(R_ / 16, 1), 256, 0, stream>>>(
            hid, ffn_W2 + l * 131072, ffn_b2 + l * 256,
            feats, ln2_g + l * 256, ln2_b + l * 256, feats);
    }

    gemm16<256, 256, 1><<<dim3(R_ / 16, 1), 256, 0, stream>>>(
        feats, out_W1, out_b1, nullptr, nullptr, nullptr, Vbuf);
    out_proj<<<R_ / 4, 256, 0, stream>>>(Vbuf, out_W2, out_b2, (float*)d_out);
}

// Round 2
// 814.247 us; speedup vs baseline: 1.7195x; 1.7195x over previous
//
#include <hip/hip_runtime.h>

#define B_ 4
#define N_ 2048
#define R_ (B_ * N_)      // 8192 rows
#define HID_ 256
#define EMB_ 64
#define IN_DIM_ 70
#define H_ 4
#define HEAD_ 64
#define FFN_ 512
#define LAYERS_ 4

typedef __attribute__((ext_vector_type(8))) short short8;
typedef __attribute__((ext_vector_type(4))) float f32x4;
typedef unsigned short ushort;

static __device__ __forceinline__ ushort f2bf(float f) {
    unsigned u = __builtin_bit_cast(unsigned, f);
    u += 0x7fffu + ((u >> 16) & 1u);   // RNE
    return (ushort)(u >> 16);
}

#define GLOAD_LDS16(g, l)                                              \
    __builtin_amdgcn_global_load_lds(                                  \
        (const __attribute__((address_space(1))) void*)(g),            \
        (__attribute__((address_space(3))) void*)(l), 16, 0, 0)

// ---------------------------------------------------------------------------
// Repack val_W [L][H][HID][HEAD] -> Wv [L][HID][H*HEAD]
// ---------------------------------------------------------------------------
__global__ __launch_bounds__(256) void repack_valW(const float* __restrict__ valW,
                                                   float* __restrict__ Wv) {
    int idx = blockIdx.x * 256 + threadIdx.x;
    int c = idx & 255;
    int f = (idx >> 8) & 255;
    int l = idx >> 16;
    int h = c >> 6, d = c & 63;
    Wv[idx] = valW[(((l * H_ + h) * HID_ + f) * HEAD_) + d];
}

// ---------------------------------------------------------------------------
// Input MLP: feats = relu(concat(xc, emb, lat) @ in_W + in_b)
// ---------------------------------------------------------------------------
__global__ __launch_bounds__(256) void input_mlp(const float* __restrict__ xc,
                                                 const float* __restrict__ emb,
                                                 const float* __restrict__ lat,
                                                 const float* __restrict__ W,
                                                 const float* __restrict__ b,
                                                 float* __restrict__ feats) {
    __shared__ float xr[8][IN_DIM_ + 2];
    int t = threadIdx.x;
    int row0 = blockIdx.x * 8;
    for (int idx = t; idx < 8 * IN_DIM_; idx += 256) {
        int r = idx / IN_DIM_, f = idx % IN_DIM_;
        int rr = row0 + r;
        float v;
        if (f < 3)       v = xc[rr * 3 + f];
        else if (f < 67) v = emb[rr * EMB_ + (f - 3)];
        else             v = lat[rr * 3 + (f - 67)];
        xr[r][f] = v;
    }
    __syncthreads();
    float acc[8] = {0.f, 0.f, 0.f, 0.f, 0.f, 0.f, 0.f, 0.f};
    for (int f = 0; f < IN_DIM_; ++f) {
        float w = W[f * HID_ + t];
#pragma unroll
        for (int r = 0; r < 8; ++r) acc[r] += xr[r][f] * w;
    }
    float bb = b[t];
#pragma unroll
    for (int r = 0; r < 8; ++r) {
        float v = acc[r] + bb;
        feats[(row0 + r) * HID_ + t] = v > 0.f ? v : 0.f;
    }
}

// ---------------------------------------------------------------------------
// GEMM: out[R][COLS] = X[R][KD] @ W[KD][COLS] (+epilogues)
// MODE 1: +bias, relu
// MODE 2: +bias, +resid, LayerNorm   (COLS==256)
// MODE 3: +bias, write TRANSPOSED bf16 Vt[b][c][n]  (COLS==256)
// ---------------------------------------------------------------------------
template <int KD, int COLS, int MODE>
__global__ __launch_bounds__(256) void gemm16(const float* __restrict__ X,
                                              const float* __restrict__ W,
                                              const float* __restrict__ bias,
                                              const float* __restrict__ resid,
                                              const float* __restrict__ g,
                                              const float* __restrict__ bln,
                                              float* __restrict__ out) {
    __shared__ float Xs[16][33];
    __shared__ float Ws[32][256];
    int t = threadIdx.x;
    int row0 = blockIdx.x * 16;
    int cbase = blockIdx.y * 256;
    int c0 = (t & 63) * 4;
    int r0 = (t >> 6) * 4;
    float acc[4][4] = {};

    for (int kt = 0; kt < KD; kt += 32) {
        {
            int idx = t;
#pragma unroll
            for (int rep = 0; rep < 2; ++rep, idx += 256) {
                int r = idx >> 5, k = idx & 31;
                Xs[r][k] = X[(row0 + r) * KD + kt + k];
            }
        }
#pragma unroll
        for (int rep = 0; rep < 8; ++rep) {
            int k = (t >> 6) + rep * 4;
            *(float4*)&Ws[k][(t & 63) * 4] =
                *(const float4*)&W[(kt + k) * COLS + cbase + (t & 63) * 4];
        }
        __syncthreads();
#pragma unroll
        for (int k = 0; k < 32; ++k) {
            float4 wv = *(float4*)&Ws[k][c0];
#pragma unroll
            for (int i = 0; i < 4; ++i) {
                float xv = Xs[r0 + i][k];
                acc[i][0] += xv * wv.x; acc[i][1] += xv * wv.y;
                acc[i][2] += xv * wv.z; acc[i][3] += xv * wv.w;
            }
        }
        __syncthreads();
    }

    if constexpr (MODE == 2) {
        float vals[4][4];
        float s1[4] = {0.f, 0.f, 0.f, 0.f}, s2[4] = {0.f, 0.f, 0.f, 0.f};
#pragma unroll
        for (int i = 0; i < 4; ++i) {
            int row = row0 + r0 + i;
#pragma unroll
            for (int j = 0; j < 4; ++j) {
                float v = acc[i][j] + bias[c0 + j] + resid[row * 256 + c0 + j];
                vals[i][j] = v;
                s1[i] += v;
                s2[i] += v * v;
            }
        }
#pragma unroll
        for (int off = 1; off < 64; off <<= 1) {
#pragma unroll
            for (int i = 0; i < 4; ++i) {
                s1[i] += __shfl_xor(s1[i], off, 64);
                s2[i] += __shfl_xor(s2[i], off, 64);
            }
        }
#pragma unroll
        for (int i = 0; i < 4; ++i) {
            float mu = s1[i] * (1.f / 256.f);
            float var = s2[i] * (1.f / 256.f) - mu * mu;
            float rstd = rsqrtf(var + 1e-5f);
            int row = row0 + r0 + i;
#pragma unroll
            for (int j = 0; j < 4; ++j) {
                out[row * 256 + c0 + j] =
                    (vals[i][j] - mu) * rstd * g[c0 + j] + bln[c0 + j];
            }
        }
    } else if constexpr (MODE == 3) {
        __shared__ ushort Ts[16][264];
#pragma unroll
        for (int i = 0; i < 4; ++i)
#pragma unroll
            for (int j = 0; j < 4; ++j)
                Ts[r0 + i][c0 + j] = f2bf(acc[i][j] + bias[c0 + j]);
        __syncthreads();
        int b = row0 >> 11;       // row0 / 2048
        int n0 = row0 & 2047;
        union { ushort us[16]; uint4 v[2]; } pk;
#pragma unroll
        for (int jj = 0; jj < 16; ++jj) pk.us[jj] = Ts[jj][t];
        ushort* Vt = (ushort*)out;
        ushort* dst = Vt + ((size_t)(b * 256 + t)) * 2048 + n0;
        *(uint4*)dst = pk.v[0];
        *(uint4*)(dst + 8) = pk.v[1];
    } else {
#pragma unroll
        for (int i = 0; i < 4; ++i) {
            int row = row0 + r0 + i;
#pragma unroll
            for (int j = 0; j < 4; ++j) {
                float v = acc[i][j] + bias[cbase + c0 + j];
                if (MODE == 1) v = fmaxf(v, 0.f);
                out[row * COLS + cbase + c0 + j] = v;
            }
        }
    }
}

// ---------------------------------------------------------------------------
// MFMA RBF attention.
// Grid (N/32, B), 512 threads = 8 waves; wave w: head h=w&3, m-half mh=w>>2.
// E computed in registers directly in A-fragment layout (lane l: row l&15,
// j = g*8+e). V staged transposed bf16 in LDS (Vt[c][j-tile]) with XOR
// swizzle so B-fragment ds_read_b128 is bank-conflict-free.
// Denominator accumulated in-register, reduced via shfl_xor over lane groups.
// ---------------------------------------------------------------------------
__global__ __launch_bounds__(512) void attn_mfma(const float* __restrict__ xc,
                                                 const ushort* __restrict__ Vt,
                                                 float* __restrict__ O) {
    __shared__ __align__(16) char VsRaw[32768];        // 256 c x 64 j bf16 (swizzled)
    __shared__ __align__(16) float cjx[64], cjy[64], cjz[64];
    __shared__ float dnm[8][16];

    int t = threadIdx.x;
    int l = t & 63;
    int w = t >> 6;
    int h = w & 3;
    int mh = w >> 2;
    int g = l >> 4;
    int b = blockIdx.y;
    int i_base = blockIdx.x * 32;

    int my_row = i_base + mh * 16 + (l & 15);
    const float* cip = &xc[(b * N_ + my_row) * 3];
    float cix = cip[0], ciy = cip[1], ciz = cip[2];

    float inv = (h == 0) ? 4.f : (h == 1) ? 1.f : (h == 2) ? 0.25f : 0.0625f;
    float ch = -inv * 1.44269504088896f;   // exp(-d2*inv) = exp2(d2*ch)

    const ushort* VtB = Vt + (size_t)b * 256 * 2048;

    f32x4 acc[4] = {};
    float dsum = 0.f;

    for (int jt = 0; jt < N_; jt += 64) {
        __syncthreads();
        if (t < 64) {
            const float* p = &xc[(b * N_ + jt + t) * 3];
            cjx[t] = p[0]; cjy[t] = p[1]; cjz[t] = p[2];
        }
        // stage V tile: 4 shots x 512 threads x 16B = 32KB, pre-swizzled source
        {
            int s = t & 7;
#pragma unroll
            for (int q = 0; q < 4; ++q) {
                int cc = q * 64 + (t >> 3);
                const ushort* src = VtB + (size_t)cc * 2048 + jt + ((s ^ (cc & 7)) << 3);
                GLOAD_LDS16(src, &VsRaw[q * 8192 + t * 16]);
            }
        }
        __syncthreads();

#pragma unroll
        for (int kk = 0; kk < 2; ++kk) {
            int j0 = kk * 32 + g * 8;
            float4 cx0 = *(const float4*)&cjx[j0];
            float4 cx1 = *(const float4*)&cjx[j0 + 4];
            float4 cy0 = *(const float4*)&cjy[j0];
            float4 cy1 = *(const float4*)&cjy[j0 + 4];
            float4 cz0 = *(const float4*)&cjz[j0];
            float4 cz1 = *(const float4*)&cjz[j0 + 4];
            float jx[8] = {cx0.x, cx0.y, cx0.z, cx0.w, cx1.x, cx1.y, cx1.z, cx1.w};
            float jy[8] = {cy0.x, cy0.y, cy0.z, cy0.w, cy1.x, cy1.y, cy1.z, cy1.w};
            float jz[8] = {cz0.x, cz0.y, cz0.z, cz0.w, cz1.x, cz1.y, cz1.z, cz1.w};
            float ex[8];
#pragma unroll
            for (int e = 0; e < 8; ++e) {
                float dx = cix - jx[e];
                float dy = ciy - jy[e];
                float dz = ciz - jz[e];
                float d2 = dx * dx + dy * dy + dz * dz;
                ex[e] = exp2f(d2 * ch);
            }
            dsum += ((ex[0] + ex[1]) + (ex[2] + ex[3])) +
                    ((ex[4] + ex[5]) + (ex[6] + ex[7]));
            short8 af;
#pragma unroll
            for (int e = 0; e < 8; ++e) af[e] = (short)f2bf(ex[e]);
            int jb = kk * 4 + g;
#pragma unroll
            for (int nn = 0; nn < 4; ++nn) {
                int c = h * 64 + nn * 16 + (l & 15);
                short8 bf = *(const short8*)&VsRaw[c * 128 + ((jb ^ (c & 7)) << 4)];
                acc[nn] = __builtin_amdgcn_mfma_f32_16x16x32_bf16(af, bf, acc[nn], 0, 0, 0);
            }
        }
    }

    // per-row denominator: reduce over the 4 lane-groups (same l&15)
    dsum += __shfl_xor(dsum, 16, 64);
    dsum += __shfl_xor(dsum, 32, 64);
    if (l < 16) dnm[w][l] = dsum;
    __syncthreads();

#pragma unroll
    for (int nn = 0; nn < 4; ++nn) {
#pragma unroll
        for (int r = 0; r < 4; ++r) {
            int ri = g * 4 + r;                       // C/D: row=(lane>>4)*4+reg
            float invd = 1.f / (dnm[w][ri] + 1e-8f);
            int row = b * N_ + i_base + mh * 16 + ri;
            O[row * 256 + h * 64 + nn * 16 + (l & 15)] = acc[nn][r] * invd;
        }
    }
}

// ---------------------------------------------------------------------------
// Final projection: out[row][0..2]
// ---------------------------------------------------------------------------
__global__ __launch_bounds__(256) void out_proj(const float* __restrict__ X,
                                                const float* __restrict__ W2,
                                                const float* __restrict__ b2,
                                                float* __restrict__ out) {
    int t = threadIdx.x;
    int lane = t & 63, w = t >> 6;
    int row = blockIdx.x * 4 + w;
    float4 x = *(const float4*)&X[row * 256 + lane * 4];
    float xv[4] = {x.x, x.y, x.z, x.w};
    float a0 = 0.f, a1 = 0.f, a2 = 0.f;
#pragma unroll
    for (int kk = 0; kk < 4; ++kk) {
        const float* wr = &W2[(lane * 4 + kk) * 3];
        a0 += xv[kk] * wr[0];
        a1 += xv[kk] * wr[1];
        a2 += xv[kk] * wr[2];
    }
#pragma unroll
    for (int off = 1; off < 64; off <<= 1) {
        a0 += __shfl_xor(a0, off, 64);
        a1 += __shfl_xor(a1, off, 64);
        a2 += __shfl_xor(a2, off, 64);
    }
    if (lane == 0) {
        out[row * 3 + 0] = a0 + b2[0];
        out[row * 3 + 1] = a1 + b2[1];
        out[row * 3 + 2] = a2 + b2[2];
    }
}

// ---------------------------------------------------------------------------
extern "C" void kernel_launch(void* const* d_in, const int* in_sizes, int n_in,
                              void* d_out, int out_size, void* d_ws, size_t ws_size,
                              hipStream_t stream) {
    const float* lat    = (const float*)d_in[0];
    const float* xc     = (const float*)d_in[1];
    const float* emb    = (const float*)d_in[2];
    const float* in_W   = (const float*)d_in[3];
    const float* in_b   = (const float*)d_in[4];
    const float* val_W  = (const float*)d_in[5];
    const float* val_b  = (const float*)d_in[6];
    const float* attn_W = (const float*)d_in[7];
    const float* attn_b = (const float*)d_in[8];
    const float* ln1_g  = (const float*)d_in[9];
    const float* ln1_b  = (const float*)d_in[10];
    const float* ln2_g  = (const float*)d_in[11];
    const float* ln2_b  = (const float*)d_in[12];
    const float* ffn_W1 = (const float*)d_in[13];
    const float* ffn_b1 = (const float*)d_in[14];
    const float* ffn_W2 = (const float*)d_in[15];
    const float* ffn_b2 = (const float*)d_in[16];
    const float* out_W1 = (const float*)d_in[17];
    const float* out_b1 = (const float*)d_in[18];
    const float* out_W2 = (const float*)d_in[19];
    const float* out_b2 = (const float*)d_in[20];

    float* ws    = (float*)d_ws;
    float* feats = ws;                        // 8192*256
    float* att   = ws + 2097152;              // 8192*256 (also out-MLP hidden)
    float* hid   = ws + 4194304;              // 8192*512
    float* Wv    = ws + 8388608;              // 4*256*256
    ushort* Vt   = (ushort*)(ws + 8650752);   // [B][256][2048] bf16 = 4MB

    repack_valW<<<1024, 256, 0, stream>>>(val_W, Wv);
    input_mlp<<<R_ / 8, 256, 0, stream>>>(xc, emb, lat, in_W, in_b, feats);

    for (int l = 0; l < LAYERS_; ++l) {
        gemm16<256, 256, 3><<<dim3(R_ / 16, 1), 256, 0, stream>>>(
            feats, Wv + l * 65536, val_b + l * 256,
            nullptr, nullptr, nullptr, (float*)Vt);
        attn_mfma<<<dim3(N_ / 32, B_), 512, 0, stream>>>(xc, Vt, att);
        gemm16<256, 256, 2><<<dim3(R_ / 16, 1), 256, 0, stream>>>(
            att, attn_W + l * 65536, attn_b + l * 256,
            feats, ln1_g + l * 256, ln1_b + l * 256, feats);
        gemm16<256, 512, 1><<<dim3(R_ / 16, 2), 256, 0, stream>>>(
            feats, ffn_W1 + l * 131072, ffn_b1 + l * 512,
            nullptr, nullptr, nullptr, hid);
        gemm16<512, 256, 2><<<dim3(R_ / 16, 1), 256, 0, stream>>>(
            hid, ffn_W2 + l * 131072, ffn_b2 + l * 256,
            feats, ln2_g + l * 256, ln2_b + l * 256, feats);
    }

    gemm16<256, 256, 1><<<dim3(R_ / 16, 1), 256, 0, stream>>>(
        feats, out_W1, out_b1, nullptr, nullptr, nullptr, att);
    out_proj<<<R_ / 4, 256, 0, stream>>>(att, out_W2, out_b2, (float*)d_out);
}

// Round 3
// 337.382 us; speedup vs baseline: 4.1499x; 2.4134x over previous
//
#include <hip/hip_runtime.h>

#define B_ 4
#define N_ 2048
#define R_ (B_ * N_)      // 8192 rows
#define HID_ 256
#define EMB_ 64
#define IN_DIM_ 70
#define H_ 4
#define HEAD_ 64
#define FFN_ 512
#define LAYERS_ 4

typedef __attribute__((ext_vector_type(8))) short short8;
typedef __attribute__((ext_vector_type(4))) float f32x4;
typedef unsigned short ushort;

static __device__ __forceinline__ ushort f2bf(float f) {
    unsigned u = __builtin_bit_cast(unsigned, f);
    u += 0x7fffu + ((u >> 16) & 1u);   // RNE
    return (ushort)(u >> 16);
}
static __device__ __forceinline__ float bf2f(ushort u) {
    unsigned x = ((unsigned)u) << 16;
    return __builtin_bit_cast(float, x);
}

#define GLOAD_LDS16(g, l)                                              \
    __builtin_amdgcn_global_load_lds(                                  \
        (const __attribute__((address_space(1))) void*)(g),            \
        (__attribute__((address_space(3))) void*)(l), 16, 0, 0)

// ---------------------------------------------------------------------------
// Pack all weights to bf16, transposed [c][k] layout, in one kernel.
// Segments: Wvt 262144 | Wat 262144 | W1t 524288 | W2t 524288 | Wo1t 65536
// ---------------------------------------------------------------------------
__global__ __launch_bounds__(256) void pack_weights(const float* __restrict__ valW,
                                                    const float* __restrict__ attnW,
                                                    const float* __restrict__ ffnW1,
                                                    const float* __restrict__ ffnW2,
                                                    const float* __restrict__ outW1,
                                                    ushort* __restrict__ wp) {
    int idx = blockIdx.x * 256 + threadIdx.x;
    float v;
    if (idx < 262144) {
        int l = idx >> 16, c = (idx >> 8) & 255, k = idx & 255;
        v = valW[((l * 4 + (c >> 6)) * 256 + k) * 64 + (c & 63)];
    } else if (idx < 524288) {
        int i2 = idx - 262144;
        int l = i2 >> 16, c = (i2 >> 8) & 255, k = i2 & 255;
        v = attnW[l * 65536 + k * 256 + c];
    } else if (idx < 1048576) {
        int i2 = idx - 524288;
        int l = i2 >> 17, c = (i2 >> 8) & 511, k = i2 & 255;
        v = ffnW1[l * 131072 + k * 512 + c];
    } else if (idx < 1572864) {
        int i2 = idx - 1048576;
        int l = i2 >> 17, c = (i2 >> 9) & 255, k = i2 & 511;
        v = ffnW2[l * 131072 + k * 256 + c];
    } else {
        int i2 = idx - 1572864;
        int c = i2 >> 8, k = i2 & 255;
        v = outW1[k * 256 + c];
    }
    wp[idx] = f2bf(v);
}

// ---------------------------------------------------------------------------
// Input MLP: feats = relu(concat @ in_W + in_b); dual write fp32 + bf16
// ---------------------------------------------------------------------------
__global__ __launch_bounds__(256) void input_mlp(const float* __restrict__ xc,
                                                 const float* __restrict__ emb,
                                                 const float* __restrict__ lat,
                                                 const float* __restrict__ W,
                                                 const float* __restrict__ b,
                                                 float* __restrict__ feats,
                                                 ushort* __restrict__ featsb) {
    __shared__ float xr[8][IN_DIM_ + 2];
    int t = threadIdx.x;
    int row0 = blockIdx.x * 8;
    for (int idx = t; idx < 8 * IN_DIM_; idx += 256) {
        int r = idx / IN_DIM_, f = idx % IN_DIM_;
        int rr = row0 + r;
        float v;
        if (f < 3)       v = xc[rr * 3 + f];
        else if (f < 67) v = emb[rr * EMB_ + (f - 3)];
        else             v = lat[rr * 3 + (f - 67)];
        xr[r][f] = v;
    }
    __syncthreads();
    float acc[8] = {0.f, 0.f, 0.f, 0.f, 0.f, 0.f, 0.f, 0.f};
    for (int f = 0; f < IN_DIM_; ++f) {
        float w = W[f * HID_ + t];
#pragma unroll
        for (int r = 0; r < 8; ++r) acc[r] += xr[r][f] * w;
    }
    float bb = b[t];
#pragma unroll
    for (int r = 0; r < 8; ++r) {
        float v = fmaxf(acc[r] + bb, 0.f);
        feats[(row0 + r) * HID_ + t] = v;
        featsb[(row0 + r) * HID_ + t] = f2bf(v);
    }
}

// ---------------------------------------------------------------------------
// MFMA bf16 GEMM. Block = 16 rows x 256 cols, 256 threads = 4 waves.
// Wave w: cols w*64..w*64+63 (N_rep=4), all 16 rows (M_rep=1).
// K staged in 64-chunks: A 2KB + B 32KB LDS, XOR-swizzled (st-16 slots).
// MODE 1: +bias, relu -> bf16 out            (FFN1; COLS may be 512)
// MODE 2: +bias,+resid,LN -> fp32 + bf16 out (attn-proj, FFN2)
// MODE 3: +bias -> transposed bf16 Vt[c][n]  (V-proj)
// MODE 4: +bias, relu, then @W2+b2 -> fp32 d_out (final, fused out-proj)
// ---------------------------------------------------------------------------
template <int KD, int COLS, int MODE>
__global__ __launch_bounds__(256) void gemmM(const ushort* __restrict__ A,
                                             const ushort* __restrict__ Bt,
                                             const float* __restrict__ bias,
                                             const float* __restrict__ resid,
                                             const float* __restrict__ lng,
                                             const float* __restrict__ lnb,
                                             ushort* __restrict__ outb,
                                             float* __restrict__ outf) {
    __shared__ __align__(16) char lds[36864];
    char* As = lds;              // 16 rows x 128B
    char* Ws = lds + 2048;       // 256 cols x 128B
    int t = threadIdx.x;
    int l = t & 63, w = t >> 6;
    int lr = l & 15, g = l >> 4;
    int row0 = blockIdx.x * 16;
    int cbase = blockIdx.y * 256;
    f32x4 acc[4] = {};

    const ushort* srcA = A + (size_t)(row0 + (t >> 3)) * KD + (((t & 7) ^ ((t >> 3) & 7)) << 3);
    const ushort* srcB[8];
#pragma unroll
    for (int q = 0; q < 8; ++q) {
        int cl = q * 32 + (t >> 3);
        srcB[q] = Bt + (size_t)(cbase + cl) * KD + (((t & 7) ^ (cl & 7)) << 3);
    }

    int sw_a = (lr & 7) << 4;
    int aoff = lr * 128;

    for (int kt = 0; kt < KD; kt += 64) {
        if (t < 128) GLOAD_LDS16(srcA, As + t * 16);
#pragma unroll
        for (int q = 0; q < 8; ++q) GLOAD_LDS16(srcB[q], Ws + q * 4096 + t * 16);
        srcA += 64;
#pragma unroll
        for (int q = 0; q < 8; ++q) srcB[q] += 64;
        __syncthreads();

        short8 a0 = *(const short8*)(As + aoff + ((g * 16) ^ sw_a));
        short8 a1 = *(const short8*)(As + aoff + ((64 + g * 16) ^ sw_a));
#pragma unroll
        for (int n = 0; n < 4; ++n) {
            int c = w * 64 + n * 16 + lr;
            const char* cb = Ws + c * 128;
            int sw = (c & 7) << 4;
            short8 b0 = *(const short8*)(cb + ((g * 16) ^ sw));
            short8 b1 = *(const short8*)(cb + ((64 + g * 16) ^ sw));
            acc[n] = __builtin_amdgcn_mfma_f32_16x16x32_bf16(a0, b0, acc[n], 0, 0, 0);
            acc[n] = __builtin_amdgcn_mfma_f32_16x16x32_bf16(a1, b1, acc[n], 0, 0, 0);
        }
        __syncthreads();
    }

    if constexpr (MODE == 1) {
#pragma unroll
        for (int n = 0; n < 4; ++n) {
            int c = w * 64 + n * 16 + lr;
            float bi = bias[cbase + c];
#pragma unroll
            for (int r = 0; r < 4; ++r) {
                int row = row0 + g * 4 + r;
                outb[(size_t)row * COLS + cbase + c] = f2bf(fmaxf(acc[n][r] + bi, 0.f));
            }
        }
    } else if constexpr (MODE == 2) {
        float* red1 = (float*)(lds + 34816);   // [16][4]
        float* red2 = (float*)(lds + 35328);
        float vals[4][4];
        float s1[4] = {0.f, 0.f, 0.f, 0.f}, s2[4] = {0.f, 0.f, 0.f, 0.f};
#pragma unroll
        for (int n = 0; n < 4; ++n) {
            int c = w * 64 + n * 16 + lr;
            float bi = bias[c];
#pragma unroll
            for (int r = 0; r < 4; ++r) {
                int row = row0 + g * 4 + r;
                float v = acc[n][r] + bi + resid[(size_t)row * 256 + c];
                vals[n][r] = v;
                s1[r] += v;
                s2[r] += v * v;
            }
        }
#pragma unroll
        for (int off = 1; off < 16; off <<= 1) {
#pragma unroll
            for (int r = 0; r < 4; ++r) {
                s1[r] += __shfl_xor(s1[r], off, 64);
                s2[r] += __shfl_xor(s2[r], off, 64);
            }
        }
        if (lr == 0) {
#pragma unroll
            for (int r = 0; r < 4; ++r) {
                red1[(g * 4 + r) * 4 + w] = s1[r];
                red2[(g * 4 + r) * 4 + w] = s2[r];
            }
        }
        __syncthreads();
        float mu[4], rstd[4];
#pragma unroll
        for (int r = 0; r < 4; ++r) {
            int rr = g * 4 + r;
            float m1 = red1[rr * 4] + red1[rr * 4 + 1] + red1[rr * 4 + 2] + red1[rr * 4 + 3];
            float m2 = red2[rr * 4] + red2[rr * 4 + 1] + red2[rr * 4 + 2] + red2[rr * 4 + 3];
            mu[r] = m1 * (1.f / 256.f);
            float var = m2 * (1.f / 256.f) - mu[r] * mu[r];
            rstd[r] = rsqrtf(var + 1e-5f);
        }
#pragma unroll
        for (int n = 0; n < 4; ++n) {
            int c = w * 64 + n * 16 + lr;
            float gg = lng[c], bb = lnb[c];
#pragma unroll
            for (int r = 0; r < 4; ++r) {
                int row = row0 + g * 4 + r;
                float o = (vals[n][r] - mu[r]) * rstd[r] * gg + bb;
                outf[(size_t)row * 256 + c] = o;
                outb[(size_t)row * 256 + c] = f2bf(o);
            }
        }
    } else if constexpr (MODE == 3) {
        ushort(*Ts)[24] = (ushort(*)[24])lds;   // [256][24] (48B stride, 16B-aligned)
#pragma unroll
        for (int n = 0; n < 4; ++n) {
            int c = w * 64 + n * 16 + lr;
            float bi = bias[c];
#pragma unroll
            for (int r = 0; r < 4; ++r)
                Ts[c][g * 4 + r] = f2bf(acc[n][r] + bi);
        }
        __syncthreads();
        {
            int c = t;
            int b = row0 >> 11;
            int n0 = row0 & 2047;
            ushort* dst = outb + ((size_t)(b * 256 + c)) * 2048 + n0;
            uint4 v0 = *(uint4*)&Ts[c][0];
            uint4 v1 = *(uint4*)&Ts[c][8];
            *(uint4*)dst = v0;
            *(uint4*)(dst + 8) = v1;
        }
    } else {  // MODE 4: relu -> LDS, then x @ out_W2 + out_b2 -> d_out
        const float* W2 = resid;    // [256][3]
        const float* b2 = lng;      // [3]
        ushort(*Ts)[264] = (ushort(*)[264])lds;  // [16][264]
#pragma unroll
        for (int n = 0; n < 4; ++n) {
            int c = w * 64 + n * 16 + lr;
            float bi = bias[c];
#pragma unroll
            for (int r = 0; r < 4; ++r)
                Ts[g * 4 + r][c] = f2bf(fmaxf(acc[n][r] + bi, 0.f));
        }
        __syncthreads();
        int row = t >> 4, s = t & 15;
        float p0 = 0.f, p1 = 0.f, p2 = 0.f;
#pragma unroll
        for (int e = 0; e < 16; ++e) {
            float x = bf2f(Ts[row][s * 16 + e]);
            const float* wr = &W2[(s * 16 + e) * 3];
            p0 += x * wr[0];
            p1 += x * wr[1];
            p2 += x * wr[2];
        }
#pragma unroll
        for (int off = 1; off < 16; off <<= 1) {
            p0 += __shfl_xor(p0, off, 64);
            p1 += __shfl_xor(p1, off, 64);
            p2 += __shfl_xor(p2, off, 64);
        }
        if (s == 0) {
            int gr = row0 + row;
            outf[gr * 3 + 0] = p0 + b2[0];
            outf[gr * 3 + 1] = p1 + b2[1];
            outf[gr * 3 + 2] = p2 + b2[2];
        }
    }
}

// ---------------------------------------------------------------------------
// MFMA RBF attention, double-buffered V staging, coords preloaded to LDS.
// Grid (N/32, B), 512 threads = 8 waves; wave w: head h=w&3, m-half mh=w>>2.
// Denominator via spare MFMA (E @ ones). Output written bf16 (attb).
// ---------------------------------------------------------------------------
__global__ __launch_bounds__(512) void attn_mfma(const float* __restrict__ xc,
                                                 const ushort* __restrict__ Vt,
                                                 ushort* __restrict__ attb) {
    __shared__ float cjx[N_], cjy[N_], cjz[N_], rj2[N_];   // 32 KB
    __shared__ __align__(16) char Vs[2][32768];            // 64 KB dbuf

    int t = threadIdx.x;
    int l = t & 63, w = t >> 6;
    int h = w & 3, mh = w >> 2;
    int g = l >> 4, lr = l & 15;
    int b = blockIdx.y;
    int i_base = blockIdx.x * 32;

    const float* xb = xc + (size_t)b * N_ * 3;
    for (int i = t; i < N_ * 3; i += 512) {
        int j = i / 3, c = i - j * 3;
        float v = xb[i];
        if (c == 0) cjx[j] = v;
        else if (c == 1) cjy[j] = v;
        else cjz[j] = v;
    }
    __syncthreads();
    for (int j = t; j < N_; j += 512)
        rj2[j] = cjx[j] * cjx[j] + cjy[j] * cjy[j] + cjz[j] * cjz[j];

    int my_row = i_base + mh * 16 + lr;
    const float* cip = &xb[my_row * 3];
    float cix = cip[0], ciy = cip[1], ciz = cip[2];
    float inv = (h == 0) ? 4.f : (h == 1) ? 1.f : (h == 2) ? 0.25f : 0.0625f;
    float ch = -inv * 1.44269504088896f;   // exp(-d2*inv) = exp2(d2*ch)
    float ax = -2.f * ch * cix, ay = -2.f * ch * ciy, az = -2.f * ch * ciz;
    float c0 = ch * (cix * cix + ciy * ciy + ciz * ciz);

    const ushort* VtB = Vt + (size_t)b * 256 * 2048;
    f32x4 acc[4] = {};
    f32x4 accd = {};
    short8 ones = {0x3F80, 0x3F80, 0x3F80, 0x3F80, 0x3F80, 0x3F80, 0x3F80, 0x3F80};

    auto STAGE = [&](int buf, int jt) {
        int s = t & 7;
#pragma unroll
        for (int q = 0; q < 4; ++q) {
            int cc = q * 64 + (t >> 3);
            const ushort* src = VtB + (size_t)cc * 2048 + jt + ((s ^ (cc & 7)) << 3);
            GLOAD_LDS16(src, &Vs[buf][q * 8192 + t * 16]);
        }
    };
    STAGE(0, 0);

    for (int tt = 0; tt < N_ / 64; ++tt) {
        __syncthreads();   // drains stage of buf[tt&1]; syncs rj2 on first iter
        if (tt + 1 < N_ / 64) STAGE((tt + 1) & 1, (tt + 1) * 64);
        const char* buf = Vs[tt & 1];
        int jt = tt * 64;
#pragma unroll
        for (int kk = 0; kk < 2; ++kk) {
            int j0 = jt + kk * 32 + g * 8;
            float4 X0 = *(float4*)&cjx[j0], X1 = *(float4*)&cjx[j0 + 4];
            float4 Y0 = *(float4*)&cjy[j0], Y1 = *(float4*)&cjy[j0 + 4];
            float4 Z0 = *(float4*)&cjz[j0], Z1 = *(float4*)&cjz[j0 + 4];
            float4 R0 = *(float4*)&rj2[j0], R1 = *(float4*)&rj2[j0 + 4];
            float jxs[8] = {X0.x, X0.y, X0.z, X0.w, X1.x, X1.y, X1.z, X1.w};
            float jys[8] = {Y0.x, Y0.y, Y0.z, Y0.w, Y1.x, Y1.y, Y1.z, Y1.w};
            float jzs[8] = {Z0.x, Z0.y, Z0.z, Z0.w, Z1.x, Z1.y, Z1.z, Z1.w};
            float r2s[8] = {R0.x, R0.y, R0.z, R0.w, R1.x, R1.y, R1.z, R1.w};
            float ex[8];
#pragma unroll
            for (int e = 0; e < 8; ++e) {
                float v = fmaf(jxs[e], ax, c0);
                v = fmaf(jys[e], ay, v);
                v = fmaf(jzs[e], az, v);
                v = fmaf(r2s[e], ch, v);
                ex[e] = exp2f(v);
            }
            union { unsigned u[4]; short8 s8; } pk;
#pragma unroll
            for (int p = 0; p < 4; ++p)
                asm("v_cvt_pk_bf16_f32 %0, %1, %2"
                    : "=v"(pk.u[p]) : "v"(ex[2 * p]), "v"(ex[2 * p + 1]));
            short8 af = pk.s8;
            accd = __builtin_amdgcn_mfma_f32_16x16x32_bf16(af, ones, accd, 0, 0, 0);
            int jb = kk * 4 + g;
#pragma unroll
            for (int nn = 0; nn < 4; ++nn) {
                int c = h * 64 + nn * 16 + lr;
                short8 bf = *(const short8*)(buf + c * 128 + ((jb ^ (c & 7)) << 4));
                acc[nn] = __builtin_amdgcn_mfma_f32_16x16x32_bf16(af, bf, acc[nn], 0, 0, 0);
            }
        }
    }

#pragma unroll
    for (int r = 0; r < 4; ++r) {
        float invd = 1.f / (accd[r] + 1e-8f);
        int row = i_base + mh * 16 + g * 4 + r;
        size_t base = ((size_t)(b * N_ + row)) * 256 + h * 64 + lr;
#pragma unroll
        for (int nn = 0; nn < 4; ++nn)
            attb[base + nn * 16] = f2bf(acc[nn][r] * invd);
    }
}

// ---------------------------------------------------------------------------
extern "C" void kernel_launch(void* const* d_in, const int* in_sizes, int n_in,
                              void* d_out, int out_size, void* d_ws, size_t ws_size,
                              hipStream_t stream) {
    const float* lat    = (const float*)d_in[0];
    const float* xc     = (const float*)d_in[1];
    const float* emb    = (const float*)d_in[2];
    const float* in_W   = (const float*)d_in[3];
    const float* in_b   = (const float*)d_in[4];
    const float* val_W  = (const float*)d_in[5];
    const float* val_b  = (const float*)d_in[6];
    const float* attn_W = (const float*)d_in[7];
    const float* attn_b = (const float*)d_in[8];
    const float* ln1_g  = (const float*)d_in[9];
    const float* ln1_b  = (const float*)d_in[10];
    const float* ln2_g  = (const float*)d_in[11];
    const float* ln2_b  = (const float*)d_in[12];
    const float* ffn_W1 = (const float*)d_in[13];
    const float* ffn_b1 = (const float*)d_in[14];
    const float* ffn_W2 = (const float*)d_in[15];
    const float* ffn_b2 = (const float*)d_in[16];
    const float* out_W1 = (const float*)d_in[17];
    const float* out_b1 = (const float*)d_in[18];
    const float* out_W2 = (const float*)d_in[19];
    const float* out_b2 = (const float*)d_in[20];

    char* W = (char*)d_ws;
    float*  feats  = (float*)W;                                // 8 MB
    ushort* featsb = (ushort*)(W + (8u << 20));                // 4 MB
    ushort* attb   = (ushort*)(W + (12u << 20));               // 4 MB
    ushort* hid    = (ushort*)(W + (16u << 20));               // 8 MB
    ushort* Vt     = (ushort*)(W + (24u << 20));               // 4 MB
    ushort* wp     = (ushort*)(W + (28u << 20));               // 3.2 MB
    ushort* Wvt  = wp;
    ushort* Wat  = wp + 262144;
    ushort* W1t  = wp + 524288;
    ushort* W2t  = wp + 1048576;
    ushort* Wo1t = wp + 1572864;

    pack_weights<<<6400, 256, 0, stream>>>(val_W, attn_W, ffn_W1, ffn_W2, out_W1, wp);
    input_mlp<<<R_ / 8, 256, 0, stream>>>(xc, emb, lat, in_W, in_b, feats, featsb);

    for (int l = 0; l < LAYERS_; ++l) {
        gemmM<256, 256, 3><<<dim3(R_ / 16, 1), 256, 0, stream>>>(
            featsb, Wvt + l * 65536, val_b + l * 256,
            nullptr, nullptr, nullptr, Vt, nullptr);
        attn_mfma<<<dim3(N_ / 32, B_), 512, 0, stream>>>(xc, Vt, attb);
        gemmM<256, 256, 2><<<dim3(R_ / 16, 1), 256, 0, stream>>>(
            attb, Wat + l * 65536, attn_b + l * 256,
            feats, ln1_g + l * 256, ln1_b + l * 256, featsb, feats);
        gemmM<256, 512, 1><<<dim3(R_ / 16, 2), 256, 0, stream>>>(
            featsb, W1t + l * 131072, ffn_b1 + l * 512,
            nullptr, nullptr, nullptr, hid, nullptr);
        gemmM<512, 256, 2><<<dim3(R_ / 16, 1), 256, 0, stream>>>(
            hid, W2t + l * 131072, ffn_b2 + l * 256,
            feats, ln2_g + l * 256, ln2_b + l * 256, featsb, feats);
    }

    gemmM<256, 256, 4><<<dim3(R_ / 16, 1), 256, 0, stream>>>(
        featsb, Wo1t, out_b1, out_W2, out_b2, nullptr, nullptr, (float*)d_out);
}